// Round 14
// baseline (360.478 us; speedup 1.0000x reference)
//
#include <hip/hip_runtime.h>
#include <cmath>

#define Bz 2
#define Sz 1024
#define Dz 1024
#define Hz 16
#define HDz 64
#define Ez 8
#define FFz 4096
#define Nz (Bz*Sz)
#define SLOTSz (2*Nz)
#define QKVSz (3*Dz)
#define EPSz 1e-5f
#define NRB 40

typedef __attribute__((ext_vector_type(8))) short bf16x8;
typedef __attribute__((ext_vector_type(4))) short bf16x4;
typedef __attribute__((ext_vector_type(4))) float f32x4;
typedef __attribute__((ext_vector_type(8))) unsigned short ushortx8;

__device__ __forceinline__ float b2f(unsigned short u){
  union { unsigned int i; float f; } x; x.i = ((unsigned int)u) << 16; return x.f;
}
__device__ __forceinline__ unsigned short f2b(float f){
  union { float f; unsigned int i; } x; x.f = f;
  unsigned int r = x.i + 0x7FFFu + ((x.i >> 16) & 1u);
  return (unsigned short)(r >> 16);
}
__device__ __forceinline__ float erf_fast(float x){
  float ax = fabsf(x);
  float t = 1.0f/(1.0f + 0.3275911f*ax);
  float p = t*(0.254829592f + t*(-0.284496736f + t*(1.421413741f +
            t*(-1.453152027f + t*1.061405429f))));
  float r = 1.0f - p*__expf(-ax*ax);
  return copysignf(r, x);
}
__device__ __forceinline__ float gelu_f(float x){
  return 0.5f*x*(1.0f + erf_fast(x*0.70710678118654752f));
}
__device__ __forceinline__ void gload16(const void* g, void* l){
  __builtin_amdgcn_global_load_lds(
    (const __attribute__((address_space(1))) unsigned int*)g,
    (__attribute__((address_space(3))) unsigned int*)l, 16, 0, 0);
}

// ---------- shared transpose body: fp32 [R][C] tile -> bf16 [C][R] ----------
__device__ __forceinline__ void transpose_body(
    const float* __restrict__ in, unsigned short* __restrict__ out,
    int R, int C, int bx, int by, int tid, float (*tile)[65])
{
  int c0 = bx*64, r0 = by*64;
  int tx = tid & 15, ty = tid >> 4;
  #pragma unroll
  for (int i = 0; i < 4; ++i) {
    float4 v = *(const float4*)(in + (size_t)(r0+ty+16*i)*C + c0 + tx*4);
    tile[ty+16*i][tx*4+0] = v.x; tile[ty+16*i][tx*4+1] = v.y;
    tile[ty+16*i][tx*4+2] = v.z; tile[ty+16*i][tx*4+3] = v.w;
  }
  __syncthreads();
  int oc = tid >> 3, og = tid & 7;
  #pragma unroll
  for (int p = 0; p < 2; ++p) {
    int c = oc + p*32;
    ushortx8 u;
    #pragma unroll
    for (int j = 0; j < 8; ++j) u[j] = f2b(tile[og*8+j][c]);
    *(ushortx8*)(out + (size_t)(c0+c)*R + r0 + og*8) = u;
  }
}

// -- fused prologue: Wq/Wk/Wv/Wo transpose + bias concat + x->bf16 + counts=0 --
__global__ __launch_bounds__(256) void prologue_k(
    const float* __restrict__ Wq, const float* __restrict__ Wk,
    const float* __restrict__ Wv, const float* __restrict__ Wo,
    const float* __restrict__ bq, const float* __restrict__ bk,
    const float* __restrict__ bv, const float* __restrict__ x,
    unsigned short* __restrict__ Wqt, unsigned short* __restrict__ Wkt,
    unsigned short* __restrict__ Wvt, unsigned short* __restrict__ Wot,
    float* __restrict__ bqkv, unsigned short* __restrict__ xb,
    int* __restrict__ counts)
{
  __shared__ float tile[64][65];
  int id = blockIdx.x, t = threadIdx.x;
  if (id < 1024) {
    int which = id >> 8, rem = id & 255;
    const float* in = (which==0)?Wq:(which==1)?Wk:(which==2)?Wv:Wo;
    unsigned short* out = (which==0)?Wqt:(which==1)?Wkt:(which==2)?Wvt:Wot;
    transpose_body(in, out, Dz, Dz, rem & 15, rem >> 4, t, tile);
  } else if (id < 1024 + 2048) {
    int i = ((id-1024)*256 + t)*4;
    float4 v = *(const float4*)(x + i);
    ushort4 o; o.x=f2b(v.x); o.y=f2b(v.y); o.z=f2b(v.z); o.w=f2b(v.w);
    *(ushort4*)(xb + i) = o;
  } else {
    int i = (id - 3072)*256 + t;
    if (i < 3072) bqkv[i] = (i < 1024) ? bq[i] : (i < 2048 ? bk[i-1024] : bv[i-2048]);
    if (id == 3072 && t < Ez) counts[t] = 0;
  }
}

// ------- MFMA 128x128xK core: m97 loop, row-contiguous coalesced staging -------
__device__ __forceinline__ void mfma_kloop(
    const unsigned short* __restrict__ pA0, const unsigned short* __restrict__ pA1,
    const unsigned short* __restrict__ pB0, const unsigned short* __restrict__ pB1,
    char* lds, int t, int K, f32x4 acc[4][4])
{
  const int lane = t & 63, w = t >> 6;
  const int wrOff = (w >> 1) * 4096;
  const int wcOff = (w & 1) * 4096;
  const int lr = lane & 15, q = lane >> 4;
  const int xq = (q ^ (lr & 3)) << 4;
  const int baseA = wrOff + lr*64 + xq;
  const int baseB = 8192 + wcOff + lr*64 + xq;
  for (int k0 = 0; k0 < K; k0 += 32) {
    __syncthreads();
    gload16(pA0 + k0, lds + t*16);
    gload16(pA1 + k0, lds + 4096 + t*16);
    gload16(pB0 + k0, lds + 8192 + t*16);
    gload16(pB1 + k0, lds + 12288 + t*16);
    __syncthreads();
    bf16x8 a[4], b[4];
    #pragma unroll
    for (int m = 0; m < 4; ++m) a[m] = *(const bf16x8*)(lds + baseA + m*1024);
    #pragma unroll
    for (int n = 0; n < 4; ++n) b[n] = *(const bf16x8*)(lds + baseB + n*1024);
    #pragma unroll
    for (int m = 0; m < 4; ++m)
      #pragma unroll
      for (int n = 0; n < 4; ++n)
        acc[m][n] = __builtin_amdgcn_mfma_f32_16x16x32_bf16(a[m], b[n], acc[m][n], 0, 0, 0);
  }
}

// ---------------- dense GEMM with optional split-K (deterministic) ----------------
__global__ __launch_bounds__(256) void gemm_proj(
    const unsigned short* __restrict__ A, const unsigned short* __restrict__ Bt,
    const float* __restrict__ bias, unsigned short* __restrict__ outb,
    int M, int Nn, int K, int KS, int mode, int doRope)
{
  __shared__ __align__(16) char lds[16384];
  const int t = threadIdx.x;
  const int nblk = Nn >> 7;
  const int chunk = blockIdx.x / nblk;
  const int n0 = (blockIdx.x - chunk*nblk) << 7;
  const int m0 = blockIdx.y << 7;
  const int Kc = K / KS;
  const int kbase = chunk * Kc;
  const int rr = t >> 2;
  const int ch = ((t & 3) ^ (rr & 3)) * 8;
  const unsigned short* pA0 = A + (size_t)(m0 + rr)*K + kbase + ch;
  const unsigned short* pA1 = pA0 + (size_t)64*K;
  const unsigned short* pB0 = Bt + (size_t)(n0 + rr)*K + kbase + ch;
  const unsigned short* pB1 = pB0 + (size_t)64*K;
  f32x4 acc[4][4] = {};
  mfma_kloop(pA0, pA1, pB0, pB1, lds, t, Kc, acc);
  const int lane = t & 63, w = t >> 6;
  const int wr = (w>>1)<<6, wc = (w&1)<<6, lq = lane>>4, lr = lane&15;
  if (mode == 0) {
    #pragma unroll
    for (int m = 0; m < 4; ++m)
      #pragma unroll
      for (int r = 0; r < 4; ++r) {
        int row = m0 + wr + m*16 + lq*4 + r;
        int s = row & (Sz-1);
        #pragma unroll
        for (int n = 0; n < 2; ++n) {
          int col = n0 + wc + n*16 + lr;
          float v0 = acc[m][n][r]   + bias[col];
          float v1 = acc[m][n+2][r] + bias[col+32];
          if (doRope && col < 2*Dz) {
            int i = n*16 + lr;
            float ang = (float)s * __powf(10000.0f, -(float)i*(1.0f/32.0f));
            float sn, cs; __sincosf(ang, &sn, &cs);
            float r0 = v0*cs - v1*sn;
            float r1 = v1*cs + v0*sn;
            v0 = r0; v1 = r1;
          }
          outb[(size_t)row*Nn + col]      = f2b(v0);
          outb[(size_t)row*Nn + col + 32] = f2b(v1);
        }
      }
  } else {
    #pragma unroll
    for (int m = 0; m < 4; ++m)
      #pragma unroll
      for (int r = 0; r < 4; ++r) {
        int row = m0 + wr + m*16 + lq*4 + r;
        #pragma unroll
        for (int n = 0; n < 4; ++n) {
          int col = n0 + wc + n*16 + lr;
          outb[((size_t)chunk*M + row)*Nn + col] = f2b(acc[m][n][r]);
        }
      }
  }
}

// ---------------- grouped MoE GEMM1 (row-block table) ----------------
__global__ __launch_bounds__(256) void moe_gemm1(
    const unsigned short* __restrict__ x1b, const unsigned short* __restrict__ W1t,
    const float* __restrict__ b1, const int* __restrict__ counts,
    const int* __restrict__ offs, const int* __restrict__ toklist,
    const int2* __restrict__ rbmap, unsigned short* __restrict__ hb)
{
  const int2 rbe = rbmap[blockIdx.y];
  if (rbe.x < 0) return;
  const int e = rbe.x, r0 = rbe.y, cnt = counts[e];
  __shared__ __align__(16) char lds[16384];
  const int t = threadIdx.x, n0 = blockIdx.x*128;
  const int rr = t >> 2;
  const int ch = ((t & 3) ^ (rr & 3)) * 8;
  const int rg0 = r0 + rr, rg1 = r0 + 64 + rr;
  const int tok0 = toklist[e*Nz + (rg0 < cnt ? rg0 : 0)];
  const int tok1 = toklist[e*Nz + (rg1 < cnt ? rg1 : 0)];
  const unsigned short* pA0 = x1b + (size_t)tok0*Dz + ch;
  const unsigned short* pA1 = x1b + (size_t)tok1*Dz + ch;
  const unsigned short* pB0 = W1t + ((size_t)e*FFz + n0 + rr)*Dz + ch;
  const unsigned short* pB1 = pB0 + (size_t)64*Dz;
  f32x4 acc[4][4] = {};
  mfma_kloop(pA0, pA1, pB0, pB1, lds, t, Dz, acc);
  const int lane = t & 63, w = t >> 6;
  const int wr = (w>>1)<<6, wc = (w&1)<<6, lq = lane>>4, lr = lane&15;
  const int base = offs[e] + r0;
  #pragma unroll
  for (int m = 0; m < 4; ++m)
    #pragma unroll
    for (int r = 0; r < 4; ++r) {
      int row = wr + m*16 + lq*4 + r;
      if (r0 + row >= cnt) continue;
      #pragma unroll
      for (int n = 0; n < 4; ++n) {
        int col = n0 + wc + n*16 + lr;
        hb[(size_t)(base+row)*FFz + col] = f2b(gelu_f(acc[m][n][r] + b1[e*FFz + col]));
      }
    }
}

// ------- grouped MoE GEMM2, split-K x4 -> per-chunk bf16 partial stores -------
__global__ __launch_bounds__(256) void moe_gemm2(
    const unsigned short* __restrict__ hb, const unsigned short* __restrict__ W2t,
    const int* __restrict__ counts, const int* __restrict__ offs,
    const int2* __restrict__ rbmap, unsigned short* __restrict__ yp)
{
  const int2 rbe = rbmap[blockIdx.y];
  if (rbe.x < 0) return;
  const int e = rbe.x, r0 = rbe.y, cnt = counts[e];
  __shared__ __align__(16) char lds[16384];
  const int t = threadIdx.x;
  const int chunk = blockIdx.x >> 3;
  const int n0 = (blockIdx.x & 7) << 7;
  const int kbase = chunk * (FFz/4);
  const int rr = t >> 2;
  const int ch = ((t & 3) ^ (rr & 3)) * 8;
  const int rg0 = r0 + rr, rg1 = r0 + 64 + rr;
  const int slot0 = offs[e] + (rg0 < cnt ? rg0 : 0);
  const int slot1 = offs[e] + (rg1 < cnt ? rg1 : 0);
  const unsigned short* pA0 = hb + (size_t)slot0*FFz + kbase + ch;
  const unsigned short* pA1 = hb + (size_t)slot1*FFz + kbase + ch;
  const unsigned short* pB0 = W2t + ((size_t)e*Dz + n0 + rr)*FFz + kbase + ch;
  const unsigned short* pB1 = pB0 + (size_t)64*FFz;
  f32x4 acc[4][4] = {};
  mfma_kloop(pA0, pA1, pB0, pB1, lds, t, FFz/4, acc);
  const int lane = t & 63, w = t >> 6;
  const int wr = (w>>1)<<6, wc = (w&1)<<6, lq = lane>>4, lr = lane&15;
  const int base = offs[e] + r0;
  #pragma unroll
  for (int m = 0; m < 4; ++m)
    #pragma unroll
    for (int r = 0; r < 4; ++r) {
      int row = wr + m*16 + lq*4 + r;
      if (r0 + row >= cnt) continue;
      #pragma unroll
      for (int n = 0; n < 4; ++n) {
        int col = n0 + wc + n*16 + lr;
        yp[((size_t)chunk*SLOTSz + base + row)*Dz + col] = f2b(acc[m][n][r]);
      }
    }
}

// ----- MEGA: attention (blocks 0..511, KVBLK=128, drain sync) + W1/W2 transpose -----
__global__ __launch_bounds__(256) void mega_k(
    const unsigned short* __restrict__ qkv, unsigned short* __restrict__ ao,
    const float* __restrict__ W1, unsigned short* __restrict__ W1t,
    const float* __restrict__ W2, unsigned short* __restrict__ W2t)
{
  __shared__ __align__(16) char smem[49152];
  const int bid = blockIdx.x;
  if (bid >= 512) {
    if (bid < 512 + 8192) {
      int rem = bid - 512; int e = rem >> 10; int r = rem & 1023;
      transpose_body(W1 + (size_t)e*Dz*FFz, W1t + (size_t)e*FFz*Dz, Dz, FFz,
                     r & 63, r >> 6, threadIdx.x, (float(*)[65])smem);
    } else {
      int rem = bid - 8704; int e = rem >> 10; int r = rem & 1023;
      transpose_body(W2 + (size_t)e*FFz*Dz, W2t + (size_t)e*Dz*FFz, FFz, Dz,
                     r & 15, r >> 4, threadIdx.x, (float(*)[65])smem);
    }
    return;
  }
  // ---- attention: XCD-swizzled bid, KVBLK=128, proven drain sync ----
  const int lb = ((bid & 7) << 6) | (bid >> 3);   // bijective on [0,512)
  char* Klds = smem;            // 16KB: [128 kv][128B], chunk-swizzled
  char* Vlds = smem + 16384;    // 16KB: subtiled for tr-read
  char* Plds = smem + 32768;    // 16KB: 4 waves x [16 q][128 kv] bf16, swizzled
  const unsigned short* q = qkv;
  const unsigned short* k = qkv + Dz;
  const unsigned short* v = qkv + 2*Dz;

  const int t = threadIdx.x;
  const int lane = t & 63, w = t >> 6;
  const int p15 = lane & 15, g = lane >> 4;
  const int bh = lb >> 4;
  const int qblk = lb & 15;
  const int b = bh >> 4, h = bh & 15;
  const size_t hoff = (size_t)h*HDz;
  const int q0 = qblk*64 + w*16;

  const size_t qrow = (size_t)(b*Sz + q0 + p15)*QKVSz + hoff;
  const bf16x8 qf0 = *(const bf16x8*)(q + qrow + 8*g);
  const bf16x8 qf1 = *(const bf16x8*)(q + qrow + 32 + 8*g);

  char* Pw = Plds + w*4096;

  float mrun = -INFINITY, lsum = 0.f;
  f32x4 acc_o[4] = {};

  const unsigned short* kbh = k + (size_t)(b*Sz)*QKVSz + hoff;
  const unsigned short* vbh = v + (size_t)(b*Sz)*QKVSz + hoff;

  for (int t0 = 0; t0 < Sz; t0 += 128) {
    __syncthreads();
    #pragma unroll
    for (int u = 0; u < 4; ++u) {
      int j = t + 256*u;
      int kkv = j >> 3, kdc = (j & 7) ^ (kkv & 7);
      gload16(kbh + (size_t)(t0 + kkv)*QKVSz + 8*kdc, Klds + j*16);
      int va = j >> 5, vbb = (j >> 3) & 3, vr = (j >> 1) & 3, vc = 8*(j & 1);
      gload16(vbh + (size_t)(t0 + 4*va + vr)*QKVSz + 16*vbb + vc, Vlds + j*16);
    }
    __syncthreads();

    f32x4 sc[8];
    #pragma unroll
    for (int mt = 0; mt < 8; ++mt) {
      int kv = mt*16 + p15;
      bf16x8 a0 = *(const bf16x8*)(Klds + kv*128 + ((g     ^ (kv & 7))*16));
      bf16x8 a1 = *(const bf16x8*)(Klds + kv*128 + (((g+4) ^ (kv & 7))*16));
      f32x4 z = {};
      z = __builtin_amdgcn_mfma_f32_16x16x32_bf16(a0, qf0, z, 0, 0, 0);
      z = __builtin_amdgcn_mfma_f32_16x16x32_bf16(a1, qf1, z, 0, 0, 0);
      sc[mt] = z;
    }

    float pmax = -INFINITY;
    #pragma unroll
    for (int mt = 0; mt < 8; ++mt)
      #pragma unroll
      for (int r = 0; r < 4; ++r) {
        sc[mt][r] *= 0.125f;
        pmax = fmaxf(pmax, sc[mt][r]);
      }
    pmax = fmaxf(pmax, __shfl_xor(pmax, 16));
    pmax = fmaxf(pmax, __shfl_xor(pmax, 32));
    float mnew = fmaxf(mrun, pmax);
    float resc = __expf(mrun - mnew);
    mrun = mnew;
    float ps = 0.f;
    #pragma unroll
    for (int mt = 0; mt < 8; ++mt) {
      float p0 = __expf(sc[mt][0] - mnew);
      float p1 = __expf(sc[mt][1] - mnew);
      float p2 = __expf(sc[mt][2] - mnew);
      float p3 = __expf(sc[mt][3] - mnew);
      ps += (p0 + p1) + (p2 + p3);
      ushort4 pk;
      pk.x = f2b(p0); pk.y = f2b(p1); pk.z = f2b(p2); pk.w = f2b(p3);
      *(ushort4*)(Pw + ((p15*256 + mt*32 + g*8) ^ ((p15 & 7) << 4))) = pk;
    }
    ps += __shfl_xor(ps, 16);
    ps += __shfl_xor(ps, 32);
    lsum = lsum*resc + ps;
    #pragma unroll
    for (int bb = 0; bb < 4; ++bb) {
      acc_o[bb][0] *= resc; acc_o[bb][1] *= resc;
      acc_o[bb][2] *= resc; acc_o[bb][3] *= resc;
    }

    #pragma unroll
    for (int kh = 0; kh < 4; ++kh) {
      #pragma unroll
      for (int bb = 0; bb < 4; ++bb) {
        const __attribute__((address_space(3))) char* vp =
          (const __attribute__((address_space(3))) char*)
            (Vlds + 4096*kh + 1024*g + 128*bb + 8*p15);
        bf16x4 v0, v1;
        asm volatile("ds_read_b64_tr_b16 %0, %2\n\t"
                     "ds_read_b64_tr_b16 %1, %2 offset:512\n\t"
                     "s_waitcnt lgkmcnt(0)"
                     : "=v"(v0), "=v"(v1) : "v"(vp) : "memory");
        __builtin_amdgcn_sched_barrier(0);
        union { bf16x4 hh[2]; bf16x8 full; } af;
        af.hh[0] = v0; af.hh[1] = v1;
        bf16x8 pf = *(const bf16x8*)(Pw + ((p15*256 + kh*64 + g*16) ^ ((p15 & 7) << 4)));
        acc_o[bb] = __builtin_amdgcn_mfma_f32_16x16x32_bf16(af.full, pf, acc_o[bb], 0, 0, 0);
      }
    }
  }

  const float inv = 1.0f / lsum;
  const size_t orow = (size_t)(b*Sz + q0 + p15)*Dz + hoff;
  #pragma unroll
  for (int bb = 0; bb < 4; ++bb) {
    ushort4 o;
    o.x = f2b(acc_o[bb][0]*inv);
    o.y = f2b(acc_o[bb][1]*inv);
    o.z = f2b(acc_o[bb][2]*inv);
    o.w = f2b(acc_o[bb][3]*inv);
    *(ushort4*)(ao + orow + 16*bb + 4*g) = o;
  }
}

// ------ LayerNorm 1 + fused gate: in = x + bo + sum4(bf16 partials) ------
__global__ __launch_bounds__(256) void ln1_k(
    const float* __restrict__ x, const float* __restrict__ bo,
    const unsigned short* __restrict__ op, const float* __restrict__ g,
    const float* __restrict__ beta, const float* __restrict__ Wg,
    const float* __restrict__ bg, float* __restrict__ outf,
    unsigned short* __restrict__ outb, int* __restrict__ counts,
    int* __restrict__ toklist, int4* __restrict__ tokinfo,
    float2* __restrict__ tokw)
{
  int n = blockIdx.x, t = threadIdx.x;
  __shared__ float red[256];
  float vals[4]; float s = 0.f;
  #pragma unroll
  for (int i = 0; i < 4; ++i) {
    int d = t + i*256;
    size_t idx = (size_t)n*Dz + d;
    float p0 = b2f(op[idx]);
    float p1 = b2f(op[(size_t)Nz*Dz + idx]);
    float p2 = b2f(op[(size_t)2*Nz*Dz + idx]);
    float p3 = b2f(op[(size_t)3*Nz*Dz + idx]);
    float xv = x[idx] + bo[d] + ((p0 + p1) + (p2 + p3));
    vals[i] = xv; s += xv;
  }
  red[t] = s; __syncthreads();
  for (int st = 128; st; st >>= 1) { if (t < st) red[t] += red[t+st]; __syncthreads(); }
  float mean = red[0] * (1.0f/Dz);
  __syncthreads();
  float vsum = 0.f;
  #pragma unroll
  for (int i = 0; i < 4; ++i){ float dd = vals[i]-mean; vsum += dd*dd; }
  red[t] = vsum; __syncthreads();
  for (int st = 128; st; st >>= 1) { if (t < st) red[t] += red[t+st]; __syncthreads(); }
  float rs = rsqrtf(red[0]*(1.0f/Dz) + EPSz);
  float ga[8] = {0,0,0,0,0,0,0,0};
  #pragma unroll
  for (int i = 0; i < 4; ++i) {
    int d = t + i*256;
    float o = (vals[i]-mean)*rs*g[d] + beta[d];
    outf[(size_t)n*Dz + d] = o;
    outb[(size_t)n*Dz + d] = f2b(o);
    const float4* wp = (const float4*)(Wg + (size_t)d*Ez);
    float4 w0 = wp[0], w1 = wp[1];
    ga[0] += o*w0.x; ga[1] += o*w0.y; ga[2] += o*w0.z; ga[3] += o*w0.w;
    ga[4] += o*w1.x; ga[5] += o*w1.y; ga[6] += o*w1.z; ga[7] += o*w1.w;
  }
  #pragma unroll
  for (int e = 0; e < 8; ++e)
    #pragma unroll
    for (int off = 32; off; off >>= 1) ga[e] += __shfl_xor(ga[e], off);
  __syncthreads();
  if ((t & 63) == 0) {
    #pragma unroll
    for (int e = 0; e < 8; ++e) red[(t >> 6)*8 + e] = ga[e];
  }
  __syncthreads();
  if (t == 0) {
    float lg[8]; float mx = -INFINITY;
    #pragma unroll
    for (int e = 0; e < 8; ++e){
      lg[e] = (red[e] + red[8+e]) + (red[16+e] + red[24+e]) + bg[e];
      mx = fmaxf(mx, lg[e]);
    }
    float p[8];
    #pragma unroll
    for (int e = 0; e < 8; ++e) p[e] = __expf(lg[e]-mx);
    int e1 = 0; float m1 = p[0];
    for (int e = 1; e < 8; ++e) if (p[e] > m1){ m1 = p[e]; e1 = e; }
    int e2 = -1; float m2 = -INFINITY;
    for (int e = 0; e < 8; ++e) if (e != e1 && p[e] > m2){ m2 = p[e]; e2 = e; }
    float inv = 1.0f/(m1+m2);
    int p1 = atomicAdd(&counts[e1], 1); toklist[e1*Nz + p1] = n;
    int p2 = atomicAdd(&counts[e2], 1); toklist[e2*Nz + p2] = n;
    tokinfo[n] = make_int4(e1, p1, e2, p2);
    tokw[n] = make_float2(m1*inv, m2*inv);
  }
}

// ---------------- prefix + row-block table ----------------
__global__ void prefix_k(const int* __restrict__ counts, int* __restrict__ offs,
                         int2* __restrict__ rbmap){
  if (threadIdx.x == 0 && blockIdx.x == 0) {
    int s = 0;
    for (int e = 0; e < Ez; ++e){ offs[e] = s; s += counts[e]; }
    offs[Ez] = s;
    int rb = 0;
    for (int e = 0; e < Ez; ++e) {
      int nrb = (counts[e] + 127) >> 7;
      for (int i = 0; i < nrb; ++i) rbmap[rb++] = make_int2(e, i*128);
    }
    for (; rb < NRB; ++rb) rbmap[rb] = make_int2(-1, 0);
  }
}

// ------- final combine + LayerNorm (b2 + fixed-order bf16 partial sum) -------
__global__ __launch_bounds__(256) void ln2_k(
    const float* __restrict__ x1, const unsigned short* __restrict__ yp,
    const float* __restrict__ b2, const int4* __restrict__ tokinfo,
    const float2* __restrict__ tokw, const int* __restrict__ offs,
    const float* __restrict__ g, const float* __restrict__ beta,
    float* __restrict__ out)
{
  int n = blockIdx.x, t = threadIdx.x;
  __shared__ float red[256];
  int4 ti = tokinfo[n]; float2 tw = tokw[n];
  const size_t s1 = (size_t)(offs[ti.x] + ti.y)*Dz;
  const size_t s2 = (size_t)(offs[ti.z] + ti.w)*Dz;
  const size_t CS = (size_t)SLOTSz*Dz;
  const float* b2a = b2 + (size_t)ti.x*Dz;
  const float* b2b = b2 + (size_t)ti.z*Dz;
  float vals[4]; float s = 0.f;
  #pragma unroll
  for (int i = 0; i < 4; ++i) {
    int d = t + i*256;
    float a0 = b2f(yp[s1 + d]);
    float a1 = b2f(yp[CS + s1 + d]);
    float a2 = b2f(yp[2*CS + s1 + d]);
    float a3 = b2f(yp[3*CS + s1 + d]);
    float c0 = b2f(yp[s2 + d]);
    float c1 = b2f(yp[CS + s2 + d]);
    float c2 = b2f(yp[2*CS + s2 + d]);
    float c3 = b2f(yp[3*CS + s2 + d]);
    float sumA = (a0 + a1) + (a2 + a3);
    float sumB = (c0 + c1) + (c2 + c3);
    float xv = x1[(size_t)n*Dz + d] + tw.x*(sumA + b2a[d]) + tw.y*(sumB + b2b[d]);
    vals[i] = xv; s += xv;
  }
  red[t] = s; __syncthreads();
  for (int st = 128; st; st >>= 1) { if (t < st) red[t] += red[t+st]; __syncthreads(); }
  float mean = red[0] * (1.0f/Dz);
  __syncthreads();
  float vsum = 0.f;
  #pragma unroll
  for (int i = 0; i < 4; ++i){ float dd = vals[i]-mean; vsum += dd*dd; }
  red[t] = vsum; __syncthreads();
  for (int st = 128; st; st >>= 1) { if (t < st) red[t] += red[t+st]; __syncthreads(); }
  float rs = rsqrtf(red[0]*(1.0f/Dz) + EPSz);
  #pragma unroll
  for (int i = 0; i < 4; ++i) {
    int d = t + i*256;
    out[(size_t)n*Dz + d] = (vals[i]-mean)*rs*g[d] + beta[d];
  }
}

extern "C" void kernel_launch(void* const* d_in, const int* in_sizes, int n_in,
                              void* d_out, int out_size, void* d_ws, size_t ws_size,
                              hipStream_t stream)
{
  const float* x  = (const float*)d_in[0];
  const float* Wq = (const float*)d_in[1];
  const float* bq = (const float*)d_in[2];
  const float* Wk = (const float*)d_in[3];
  const float* bk = (const float*)d_in[4];
  const float* Wv = (const float*)d_in[5];
  const float* bv = (const float*)d_in[6];
  const float* Wo = (const float*)d_in[7];
  const float* bo = (const float*)d_in[8];
  const float* Wg = (const float*)d_in[9];
  const float* bg = (const float*)d_in[10];
  const float* W1 = (const float*)d_in[11];
  const float* b1 = (const float*)d_in[12];
  const float* W2 = (const float*)d_in[13];
  const float* b2 = (const float*)d_in[14];
  const float* g1 = (const float*)d_in[15];
  const float* be1= (const float*)d_in[16];
  const float* g2 = (const float*)d_in[17];
  const float* be2= (const float*)d_in[18];
  float* out = (float*)d_out;

  const size_t PD = (size_t)Dz*Dz;
  const size_t ND = (size_t)Nz*Dz;
  unsigned short* Wqt = (unsigned short*)d_ws;
  unsigned short* Wkt = Wqt + PD;
  unsigned short* Wvt = Wkt + PD;
  unsigned short* Wot = Wvt + PD;
  unsigned short* W1t = Wot + PD;
  unsigned short* W2t = W1t + (size_t)Ez*FFz*Dz;
  unsigned short* hb  = W2t + (size_t)Ez*FFz*Dz;
  unsigned short* xb  = hb  + (size_t)SLOTSz*FFz;
  unsigned short* qkvb= xb  + ND;                 // [Nz][3072]
  unsigned short* aob = qkvb + (size_t)Nz*QKVSz;
  unsigned short* x1b = aob + ND;
  float* x1 = (float*)(x1b + ND);
  unsigned short* yp = (unsigned short*)(x1 + ND); // [4][SLOTS][Dz] bf16 (32MB)
  unsigned short* op = yp;                         // alias: [4][Nz][Dz] bf16
  float* bqkv = (float*)(yp + (size_t)4*SLOTSz*Dz);
  int4*  tokinfo = (int4*)(bqkv + QKVSz);
  float2* tokw   = (float2*)(tokinfo + Nz);
  int* counts  = (int*)(tokw + Nz);
  int* offs    = counts + Ez;
  int* toklist = offs + Ez + 1;
  int2* rbmap  = (int2*)(toklist + Ez*Nz);

  dim3 blk(256);
  // fused prologue: Wq/Wk/Wv/Wo transpose + bias concat + x->bf16 + counts=0
  prologue_k<<<3084, blk, 0, stream>>>(Wq, Wk, Wv, Wo, bq, bk, bv, x,
                                       Wqt, Wkt, Wvt, Wot, bqkv, xb, counts);

  // fused QKV with fused RoPE: [2048,1024] @ [1024,3072] -> qkvb
  gemm_proj<<<dim3(QKVSz/128, Nz/128), blk, 0, stream>>>(
      xb, Wqt, bqkv, qkvb, Nz, QKVSz, Dz, 1, 0, 1);

  // MEGA: attention (KVBLK=128, XCD-swizzled) + W1/W2 transpose-convert
  mega_k<<<512 + 2*8192, blk, 0, stream>>>(qkvb, aob, W1, W1t, W2, W2t);

  // O projection: split-K x4 deterministic bf16 partials -> op[4][Nz][Dz]
  gemm_proj<<<dim3((Dz/128)*4, Nz/128), blk, 0, stream>>>(
      aob, Wot, nullptr, op, Nz, Dz, Dz, 4, 1, 0);

  // ln1 + fused gate/top-2/bucketing
  ln1_k<<<Nz, blk, 0, stream>>>(x, bo, op, g1, be1, Wg, bg, x1, x1b,
                                counts, toklist, tokinfo, tokw);
  prefix_k<<<1, dim3(64), 0, stream>>>(counts, offs, rbmap);
  moe_gemm1<<<dim3(FFz/128, NRB), blk, 0, stream>>>(x1b, W1t, b1, counts, offs, toklist, rbmap, hb);
  moe_gemm2<<<dim3((Dz/128)*4, NRB), blk, 0, stream>>>(hb, W2t, counts, offs, rbmap, yp);
  ln2_k<<<Nz, blk, 0, stream>>>(x1, yp, b2, tokinfo, tokw, offs, g2, be2, out);
}

// Round 15
// 354.064 us; speedup vs baseline: 1.0181x; 1.0181x over previous
//
#include <hip/hip_runtime.h>
#include <cmath>

#define Bz 2
#define Sz 1024
#define Dz 1024
#define Hz 16
#define HDz 64
#define Ez 8
#define FFz 4096
#define Nz (Bz*Sz)
#define SLOTSz (2*Nz)
#define QKVSz (3*Dz)
#define EPSz 1e-5f
#define NRB 40

typedef __attribute__((ext_vector_type(8))) short bf16x8;
typedef __attribute__((ext_vector_type(4))) short bf16x4;
typedef __attribute__((ext_vector_type(4))) float f32x4;
typedef __attribute__((ext_vector_type(8))) unsigned short ushortx8;

__device__ __forceinline__ float b2f(unsigned short u){
  union { unsigned int i; float f; } x; x.i = ((unsigned int)u) << 16; return x.f;
}
__device__ __forceinline__ unsigned short f2b(float f){
  union { float f; unsigned int i; } x; x.f = f;
  unsigned int r = x.i + 0x7FFFu + ((x.i >> 16) & 1u);
  return (unsigned short)(r >> 16);
}
__device__ __forceinline__ float erf_fast(float x){
  float ax = fabsf(x);
  float t = 1.0f/(1.0f + 0.3275911f*ax);
  float p = t*(0.254829592f + t*(-0.284496736f + t*(1.421413741f +
            t*(-1.453152027f + t*1.061405429f))));
  float r = 1.0f - p*__expf(-ax*ax);
  return copysignf(r, x);
}
__device__ __forceinline__ float gelu_f(float x){
  return 0.5f*x*(1.0f + erf_fast(x*0.70710678118654752f));
}
__device__ __forceinline__ void gload16(const void* g, void* l){
  __builtin_amdgcn_global_load_lds(
    (const __attribute__((address_space(1))) unsigned int*)g,
    (__attribute__((address_space(3))) unsigned int*)l, 16, 0, 0);
}

// ---------- shared transpose body: fp32 [R][C] tile -> bf16 [C][R] ----------
__device__ __forceinline__ void transpose_body(
    const float* __restrict__ in, unsigned short* __restrict__ out,
    int R, int C, int bx, int by, int tid, float (*tile)[65])
{
  int c0 = bx*64, r0 = by*64;
  int tx = tid & 15, ty = tid >> 4;
  #pragma unroll
  for (int i = 0; i < 4; ++i) {
    float4 v = *(const float4*)(in + (size_t)(r0+ty+16*i)*C + c0 + tx*4);
    tile[ty+16*i][tx*4+0] = v.x; tile[ty+16*i][tx*4+1] = v.y;
    tile[ty+16*i][tx*4+2] = v.z; tile[ty+16*i][tx*4+3] = v.w;
  }
  __syncthreads();
  int oc = tid >> 3, og = tid & 7;
  #pragma unroll
  for (int p = 0; p < 2; ++p) {
    int c = oc + p*32;
    ushortx8 u;
    #pragma unroll
    for (int j = 0; j < 8; ++j) u[j] = f2b(tile[og*8+j][c]);
    *(ushortx8*)(out + (size_t)(c0+c)*R + r0 + og*8) = u;
  }
}

// -- fused prologue: Wq/Wk/Wv/Wo transpose + bias concat + x->bf16 + counts=0 --
__global__ __launch_bounds__(256) void prologue_k(
    const float* __restrict__ Wq, const float* __restrict__ Wk,
    const float* __restrict__ Wv, const float* __restrict__ Wo,
    const float* __restrict__ bq, const float* __restrict__ bk,
    const float* __restrict__ bv, const float* __restrict__ x,
    unsigned short* __restrict__ Wqt, unsigned short* __restrict__ Wkt,
    unsigned short* __restrict__ Wvt, unsigned short* __restrict__ Wot,
    float* __restrict__ bqkv, unsigned short* __restrict__ xb,
    int* __restrict__ counts)
{
  __shared__ float tile[64][65];
  int id = blockIdx.x, t = threadIdx.x;
  if (id < 1024) {
    int which = id >> 8, rem = id & 255;
    const float* in = (which==0)?Wq:(which==1)?Wk:(which==2)?Wv:Wo;
    unsigned short* out = (which==0)?Wqt:(which==1)?Wkt:(which==2)?Wvt:Wot;
    transpose_body(in, out, Dz, Dz, rem & 15, rem >> 4, t, tile);
  } else if (id < 1024 + 2048) {
    int i = ((id-1024)*256 + t)*4;
    float4 v = *(const float4*)(x + i);
    ushort4 o; o.x=f2b(v.x); o.y=f2b(v.y); o.z=f2b(v.z); o.w=f2b(v.w);
    *(ushort4*)(xb + i) = o;
  } else {
    int i = (id - 3072)*256 + t;
    if (i < 3072) bqkv[i] = (i < 1024) ? bq[i] : (i < 2048 ? bk[i-1024] : bv[i-2048]);
    if (id == 3072 && t < Ez) counts[t] = 0;
  }
}

// ------- MFMA 128x128xK core: m97 loop, row-contiguous coalesced staging -------
__device__ __forceinline__ void mfma_kloop(
    const unsigned short* __restrict__ pA0, const unsigned short* __restrict__ pA1,
    const unsigned short* __restrict__ pB0, const unsigned short* __restrict__ pB1,
    char* lds, int t, int K, f32x4 acc[4][4])
{
  const int lane = t & 63, w = t >> 6;
  const int wrOff = (w >> 1) * 4096;
  const int wcOff = (w & 1) * 4096;
  const int lr = lane & 15, q = lane >> 4;
  const int xq = (q ^ (lr & 3)) << 4;
  const int baseA = wrOff + lr*64 + xq;
  const int baseB = 8192 + wcOff + lr*64 + xq;
  for (int k0 = 0; k0 < K; k0 += 32) {
    __syncthreads();
    gload16(pA0 + k0, lds + t*16);
    gload16(pA1 + k0, lds + 4096 + t*16);
    gload16(pB0 + k0, lds + 8192 + t*16);
    gload16(pB1 + k0, lds + 12288 + t*16);
    __syncthreads();
    bf16x8 a[4], b[4];
    #pragma unroll
    for (int m = 0; m < 4; ++m) a[m] = *(const bf16x8*)(lds + baseA + m*1024);
    #pragma unroll
    for (int n = 0; n < 4; ++n) b[n] = *(const bf16x8*)(lds + baseB + n*1024);
    #pragma unroll
    for (int m = 0; m < 4; ++m)
      #pragma unroll
      for (int n = 0; n < 4; ++n)
        acc[m][n] = __builtin_amdgcn_mfma_f32_16x16x32_bf16(a[m], b[n], acc[m][n], 0, 0, 0);
  }
}

// ---------------- dense GEMM with optional split-K (deterministic) ----------------
__global__ __launch_bounds__(256) void gemm_proj(
    const unsigned short* __restrict__ A, const unsigned short* __restrict__ Bt,
    const float* __restrict__ bias, unsigned short* __restrict__ outb,
    int M, int Nn, int K, int KS, int mode, int doRope)
{
  __shared__ __align__(16) char lds[16384];
  const int t = threadIdx.x;
  const int nblk = Nn >> 7;
  const int chunk = blockIdx.x / nblk;
  const int n0 = (blockIdx.x - chunk*nblk) << 7;
  const int m0 = blockIdx.y << 7;
  const int Kc = K / KS;
  const int kbase = chunk * Kc;
  const int rr = t >> 2;
  const int ch = ((t & 3) ^ (rr & 3)) * 8;
  const unsigned short* pA0 = A + (size_t)(m0 + rr)*K + kbase + ch;
  const unsigned short* pA1 = pA0 + (size_t)64*K;
  const unsigned short* pB0 = Bt + (size_t)(n0 + rr)*K + kbase + ch;
  const unsigned short* pB1 = pB0 + (size_t)64*K;
  f32x4 acc[4][4] = {};
  mfma_kloop(pA0, pA1, pB0, pB1, lds, t, Kc, acc);
  const int lane = t & 63, w = t >> 6;
  const int wr = (w>>1)<<6, wc = (w&1)<<6, lq = lane>>4, lr = lane&15;
  if (mode == 0) {
    #pragma unroll
    for (int m = 0; m < 4; ++m)
      #pragma unroll
      for (int r = 0; r < 4; ++r) {
        int row = m0 + wr + m*16 + lq*4 + r;
        int s = row & (Sz-1);
        #pragma unroll
        for (int n = 0; n < 2; ++n) {
          int col = n0 + wc + n*16 + lr;
          float v0 = acc[m][n][r]   + bias[col];
          float v1 = acc[m][n+2][r] + bias[col+32];
          if (doRope && col < 2*Dz) {
            int i = n*16 + lr;
            float ang = (float)s * __powf(10000.0f, -(float)i*(1.0f/32.0f));
            float sn, cs; __sincosf(ang, &sn, &cs);
            float r0 = v0*cs - v1*sn;
            float r1 = v1*cs + v0*sn;
            v0 = r0; v1 = r1;
          }
          outb[(size_t)row*Nn + col]      = f2b(v0);
          outb[(size_t)row*Nn + col + 32] = f2b(v1);
        }
      }
  } else {
    #pragma unroll
    for (int m = 0; m < 4; ++m)
      #pragma unroll
      for (int r = 0; r < 4; ++r) {
        int row = m0 + wr + m*16 + lq*4 + r;
        #pragma unroll
        for (int n = 0; n < 4; ++n) {
          int col = n0 + wc + n*16 + lr;
          outb[((size_t)chunk*M + row)*Nn + col] = f2b(acc[m][n][r]);
        }
      }
  }
}

// ---------------- grouped MoE GEMM1 (row-block table) ----------------
__global__ __launch_bounds__(256) void moe_gemm1(
    const unsigned short* __restrict__ x1b, const unsigned short* __restrict__ W1t,
    const float* __restrict__ b1, const int* __restrict__ counts,
    const int* __restrict__ offs, const int* __restrict__ toklist,
    const int2* __restrict__ rbmap, unsigned short* __restrict__ hb)
{
  const int2 rbe = rbmap[blockIdx.y];
  if (rbe.x < 0) return;
  const int e = rbe.x, r0 = rbe.y, cnt = counts[e];
  __shared__ __align__(16) char lds[16384];
  const int t = threadIdx.x, n0 = blockIdx.x*128;
  const int rr = t >> 2;
  const int ch = ((t & 3) ^ (rr & 3)) * 8;
  const int rg0 = r0 + rr, rg1 = r0 + 64 + rr;
  const int tok0 = toklist[e*Nz + (rg0 < cnt ? rg0 : 0)];
  const int tok1 = toklist[e*Nz + (rg1 < cnt ? rg1 : 0)];
  const unsigned short* pA0 = x1b + (size_t)tok0*Dz + ch;
  const unsigned short* pA1 = x1b + (size_t)tok1*Dz + ch;
  const unsigned short* pB0 = W1t + ((size_t)e*FFz + n0 + rr)*Dz + ch;
  const unsigned short* pB1 = pB0 + (size_t)64*Dz;
  f32x4 acc[4][4] = {};
  mfma_kloop(pA0, pA1, pB0, pB1, lds, t, Dz, acc);
  const int lane = t & 63, w = t >> 6;
  const int wr = (w>>1)<<6, wc = (w&1)<<6, lq = lane>>4, lr = lane&15;
  const int base = offs[e] + r0;
  #pragma unroll
  for (int m = 0; m < 4; ++m)
    #pragma unroll
    for (int r = 0; r < 4; ++r) {
      int row = wr + m*16 + lq*4 + r;
      if (r0 + row >= cnt) continue;
      #pragma unroll
      for (int n = 0; n < 4; ++n) {
        int col = n0 + wc + n*16 + lr;
        hb[(size_t)(base+row)*FFz + col] = f2b(gelu_f(acc[m][n][r] + b1[e*FFz + col]));
      }
    }
}

// ------- grouped MoE GEMM2, split-K x4 -> per-chunk bf16 partial stores -------
__global__ __launch_bounds__(256) void moe_gemm2(
    const unsigned short* __restrict__ hb, const unsigned short* __restrict__ W2t,
    const int* __restrict__ counts, const int* __restrict__ offs,
    const int2* __restrict__ rbmap, unsigned short* __restrict__ yp)
{
  const int2 rbe = rbmap[blockIdx.y];
  if (rbe.x < 0) return;
  const int e = rbe.x, r0 = rbe.y, cnt = counts[e];
  __shared__ __align__(16) char lds[16384];
  const int t = threadIdx.x;
  const int chunk = blockIdx.x >> 3;
  const int n0 = (blockIdx.x & 7) << 7;
  const int kbase = chunk * (FFz/4);
  const int rr = t >> 2;
  const int ch = ((t & 3) ^ (rr & 3)) * 8;
  const int rg0 = r0 + rr, rg1 = r0 + 64 + rr;
  const int slot0 = offs[e] + (rg0 < cnt ? rg0 : 0);
  const int slot1 = offs[e] + (rg1 < cnt ? rg1 : 0);
  const unsigned short* pA0 = hb + (size_t)slot0*FFz + kbase + ch;
  const unsigned short* pA1 = hb + (size_t)slot1*FFz + kbase + ch;
  const unsigned short* pB0 = W2t + ((size_t)e*Dz + n0 + rr)*FFz + kbase + ch;
  const unsigned short* pB1 = pB0 + (size_t)64*FFz;
  f32x4 acc[4][4] = {};
  mfma_kloop(pA0, pA1, pB0, pB1, lds, t, FFz/4, acc);
  const int lane = t & 63, w = t >> 6;
  const int wr = (w>>1)<<6, wc = (w&1)<<6, lq = lane>>4, lr = lane&15;
  const int base = offs[e] + r0;
  #pragma unroll
  for (int m = 0; m < 4; ++m)
    #pragma unroll
    for (int r = 0; r < 4; ++r) {
      int row = wr + m*16 + lq*4 + r;
      if (r0 + row >= cnt) continue;
      #pragma unroll
      for (int n = 0; n < 4; ++n) {
        int col = n0 + wc + n*16 + lr;
        yp[((size_t)chunk*SLOTSz + base + row)*Dz + col] = f2b(acc[m][n][r]);
      }
    }
}

// ----- MEGA: attention (blocks 0..511, KVBLK=64, P aliased onto K, 16.6KB LDS)
//       + W1/W2 transpose-convert (rest) -----
__global__ __launch_bounds__(256) void mega_k(
    const unsigned short* __restrict__ qkv, unsigned short* __restrict__ ao,
    const float* __restrict__ W1, unsigned short* __restrict__ W1t,
    const float* __restrict__ W2, unsigned short* __restrict__ W2t)
{
  __shared__ __align__(16) char smem[16640];   // max(attn 16KB, tile[64][65] 16.64KB)
  const int bid = blockIdx.x;
  if (bid >= 512) {
    if (bid < 512 + 8192) {
      int rem = bid - 512; int e = rem >> 10; int r = rem & 1023;
      transpose_body(W1 + (size_t)e*Dz*FFz, W1t + (size_t)e*FFz*Dz, Dz, FFz,
                     r & 63, r >> 6, threadIdx.x, (float(*)[65])smem);
    } else {
      int rem = bid - 8704; int e = rem >> 10; int r = rem & 1023;
      transpose_body(W2 + (size_t)e*FFz*Dz, W2t + (size_t)e*Dz*FFz, FFz, Dz,
                     r & 15, r >> 4, threadIdx.x, (float(*)[65])smem);
    }
    return;
  }
  // ---- attention: XCD-swizzled bid, KVBLK=64, P strip aliased onto K ----
  const int lb = ((bid & 7) << 6) | (bid >> 3);   // bijective on [0,512)
  char* Klds = smem;            // 8KB: [64 kv][128B], chunk-swizzled (dead after QK^T)
  char* Vlds = smem + 8192;     // 8KB: subtiled for tr-read
  const unsigned short* q = qkv;
  const unsigned short* k = qkv + Dz;
  const unsigned short* v = qkv + 2*Dz;

  const int t = threadIdx.x;
  const int lane = t & 63, w = t >> 6;
  const int p15 = lane & 15, g = lane >> 4;
  const int bh = lb >> 4;
  const int qblk = lb & 15;
  const int b = bh >> 4, h = bh & 15;
  const size_t hoff = (size_t)h*HDz;
  const int q0 = qblk*64 + w*16;

  const size_t qrow = (size_t)(b*Sz + q0 + p15)*QKVSz + hoff;
  const bf16x8 qf0 = *(const bf16x8*)(q + qrow + 8*g);
  const bf16x8 qf1 = *(const bf16x8*)(q + qrow + 32 + 8*g);

  char* Pw = Klds + w*2048;     // P strip aliases K (written after post-QK barrier)

  float mrun = -INFINITY, lsum = 0.f;
  f32x4 acc_o[4] = {};

  const unsigned short* kbh = k + (size_t)(b*Sz)*QKVSz + hoff;
  const unsigned short* vbh = v + (size_t)(b*Sz)*QKVSz + hoff;

  for (int t0 = 0; t0 < Sz; t0 += 64) {
    __syncthreads();   // prev tile's P/V reads complete before restaging
    #pragma unroll
    for (int u = 0; u < 2; ++u) {
      int j = t + 256*u;
      int kkv = j >> 3, kdc = (j & 7) ^ (kkv & 7);
      gload16(kbh + (size_t)(t0 + kkv)*QKVSz + 8*kdc, Klds + j*16);
      int va = j >> 5, vbb = (j >> 3) & 3, vr = (j >> 1) & 3, vc = 8*(j & 1);
      gload16(vbh + (size_t)(t0 + 4*va + vr)*QKVSz + 16*vbb + vc, Vlds + j*16);
    }
    __syncthreads();

    f32x4 sc[4];
    #pragma unroll
    for (int mt = 0; mt < 4; ++mt) {
      int kv = mt*16 + p15;
      bf16x8 a0 = *(const bf16x8*)(Klds + kv*128 + ((g     ^ (kv & 7))*16));
      bf16x8 a1 = *(const bf16x8*)(Klds + kv*128 + (((g+4) ^ (kv & 7))*16));
      f32x4 z = {};
      z = __builtin_amdgcn_mfma_f32_16x16x32_bf16(a0, qf0, z, 0, 0, 0);
      z = __builtin_amdgcn_mfma_f32_16x16x32_bf16(a1, qf1, z, 0, 0, 0);
      sc[mt] = z;
    }

    float pmax = -INFINITY;
    #pragma unroll
    for (int mt = 0; mt < 4; ++mt)
      #pragma unroll
      for (int r = 0; r < 4; ++r) {
        sc[mt][r] *= 0.125f;
        pmax = fmaxf(pmax, sc[mt][r]);
      }
    pmax = fmaxf(pmax, __shfl_xor(pmax, 16));
    pmax = fmaxf(pmax, __shfl_xor(pmax, 32));
    float mnew = fmaxf(mrun, pmax);
    float resc = __expf(mrun - mnew);
    mrun = mnew;

    __syncthreads();   // all waves finished reading K: safe to overwrite with P

    float ps = 0.f;
    #pragma unroll
    for (int mt = 0; mt < 4; ++mt) {
      float p0 = __expf(sc[mt][0] - mnew);
      float p1 = __expf(sc[mt][1] - mnew);
      float p2 = __expf(sc[mt][2] - mnew);
      float p3 = __expf(sc[mt][3] - mnew);
      ps += (p0 + p1) + (p2 + p3);
      ushort4 pk;
      pk.x = f2b(p0); pk.y = f2b(p1); pk.z = f2b(p2); pk.w = f2b(p3);
      *(ushort4*)(Pw + ((p15*128 + mt*32 + g*8) ^ ((p15 & 7) << 4))) = pk;
    }
    ps += __shfl_xor(ps, 16);
    ps += __shfl_xor(ps, 32);
    lsum = lsum*resc + ps;
    #pragma unroll
    for (int bb = 0; bb < 4; ++bb) {
      acc_o[bb][0] *= resc; acc_o[bb][1] *= resc;
      acc_o[bb][2] *= resc; acc_o[bb][3] *= resc;
    }

    #pragma unroll
    for (int bb = 0; bb < 4; ++bb) {
      #pragma unroll
      for (int kh = 0; kh < 2; ++kh) {
        const __attribute__((address_space(3))) char* vp =
          (const __attribute__((address_space(3))) char*)
            (Vlds + 4096*kh + 1024*g + 128*bb + 8*p15);
        bf16x4 v0, v1;
        asm volatile("ds_read_b64_tr_b16 %0, %2\n\t"
                     "ds_read_b64_tr_b16 %1, %2 offset:512\n\t"
                     "s_waitcnt lgkmcnt(0)"
                     : "=v"(v0), "=v"(v1) : "v"(vp) : "memory");
        __builtin_amdgcn_sched_barrier(0);
        union { bf16x4 hh[2]; bf16x8 full; } af;
        af.hh[0] = v0; af.hh[1] = v1;
        bf16x8 pf = *(const bf16x8*)(Pw + ((p15*128 + kh*64 + g*16) ^ ((p15 & 7) << 4)));
        acc_o[bb] = __builtin_amdgcn_mfma_f32_16x16x32_bf16(af.full, pf, acc_o[bb], 0, 0, 0);
      }
    }
  }

  const float inv = 1.0f / lsum;
  const size_t orow = (size_t)(b*Sz + q0 + p15)*Dz + hoff;
  #pragma unroll
  for (int bb = 0; bb < 4; ++bb) {
    ushort4 o;
    o.x = f2b(acc_o[bb][0]*inv);
    o.y = f2b(acc_o[bb][1]*inv);
    o.z = f2b(acc_o[bb][2]*inv);
    o.w = f2b(acc_o[bb][3]*inv);
    *(ushort4*)(ao + orow + 16*bb + 4*g) = o;
  }
}

// ------ LayerNorm 1 + fused gate: in = x + bo + sum4(bf16 partials) ------
__global__ __launch_bounds__(256) void ln1_k(
    const float* __restrict__ x, const float* __restrict__ bo,
    const unsigned short* __restrict__ op, const float* __restrict__ g,
    const float* __restrict__ beta, const float* __restrict__ Wg,
    const float* __restrict__ bg, float* __restrict__ outf,
    unsigned short* __restrict__ outb, int* __restrict__ counts,
    int* __restrict__ toklist, int4* __restrict__ tokinfo,
    float2* __restrict__ tokw)
{
  int n = blockIdx.x, t = threadIdx.x;
  __shared__ float red[256];
  float vals[4]; float s = 0.f;
  #pragma unroll
  for (int i = 0; i < 4; ++i) {
    int d = t + i*256;
    size_t idx = (size_t)n*Dz + d;
    float p0 = b2f(op[idx]);
    float p1 = b2f(op[(size_t)Nz*Dz + idx]);
    float p2 = b2f(op[(size_t)2*Nz*Dz + idx]);
    float p3 = b2f(op[(size_t)3*Nz*Dz + idx]);
    float xv = x[idx] + bo[d] + ((p0 + p1) + (p2 + p3));
    vals[i] = xv; s += xv;
  }
  red[t] = s; __syncthreads();
  for (int st = 128; st; st >>= 1) { if (t < st) red[t] += red[t+st]; __syncthreads(); }
  float mean = red[0] * (1.0f/Dz);
  __syncthreads();
  float vsum = 0.f;
  #pragma unroll
  for (int i = 0; i < 4; ++i){ float dd = vals[i]-mean; vsum += dd*dd; }
  red[t] = vsum; __syncthreads();
  for (int st = 128; st; st >>= 1) { if (t < st) red[t] += red[t+st]; __syncthreads(); }
  float rs = rsqrtf(red[0]*(1.0f/Dz) + EPSz);
  float ga[8] = {0,0,0,0,0,0,0,0};
  #pragma unroll
  for (int i = 0; i < 4; ++i) {
    int d = t + i*256;
    float o = (vals[i]-mean)*rs*g[d] + beta[d];
    outf[(size_t)n*Dz + d] = o;
    outb[(size_t)n*Dz + d] = f2b(o);
    const float4* wp = (const float4*)(Wg + (size_t)d*Ez);
    float4 w0 = wp[0], w1 = wp[1];
    ga[0] += o*w0.x; ga[1] += o*w0.y; ga[2] += o*w0.z; ga[3] += o*w0.w;
    ga[4] += o*w1.x; ga[5] += o*w1.y; ga[6] += o*w1.z; ga[7] += o*w1.w;
  }
  #pragma unroll
  for (int e = 0; e < 8; ++e)
    #pragma unroll
    for (int off = 32; off; off >>= 1) ga[e] += __shfl_xor(ga[e], off);
  __syncthreads();
  if ((t & 63) == 0) {
    #pragma unroll
    for (int e = 0; e < 8; ++e) red[(t >> 6)*8 + e] = ga[e];
  }
  __syncthreads();
  if (t == 0) {
    float lg[8]; float mx = -INFINITY;
    #pragma unroll
    for (int e = 0; e < 8; ++e){
      lg[e] = (red[e] + red[8+e]) + (red[16+e] + red[24+e]) + bg[e];
      mx = fmaxf(mx, lg[e]);
    }
    float p[8];
    #pragma unroll
    for (int e = 0; e < 8; ++e) p[e] = __expf(lg[e]-mx);
    int e1 = 0; float m1 = p[0];
    for (int e = 1; e < 8; ++e) if (p[e] > m1){ m1 = p[e]; e1 = e; }
    int e2 = -1; float m2 = -INFINITY;
    for (int e = 0; e < 8; ++e) if (e != e1 && p[e] > m2){ m2 = p[e]; e2 = e; }
    float inv = 1.0f/(m1+m2);
    int p1 = atomicAdd(&counts[e1], 1); toklist[e1*Nz + p1] = n;
    int p2 = atomicAdd(&counts[e2], 1); toklist[e2*Nz + p2] = n;
    tokinfo[n] = make_int4(e1, p1, e2, p2);
    tokw[n] = make_float2(m1*inv, m2*inv);
  }
}

// ---------------- prefix + row-block table ----------------
__global__ void prefix_k(const int* __restrict__ counts, int* __restrict__ offs,
                         int2* __restrict__ rbmap){
  if (threadIdx.x == 0 && blockIdx.x == 0) {
    int s = 0;
    for (int e = 0; e < Ez; ++e){ offs[e] = s; s += counts[e]; }
    offs[Ez] = s;
    int rb = 0;
    for (int e = 0; e < Ez; ++e) {
      int nrb = (counts[e] + 127) >> 7;
      for (int i = 0; i < nrb; ++i) rbmap[rb++] = make_int2(e, i*128);
    }
    for (; rb < NRB; ++rb) rbmap[rb] = make_int2(-1, 0);
  }
}

// ------- final combine + LayerNorm (b2 + fixed-order bf16 partial sum) -------
__global__ __launch_bounds__(256) void ln2_k(
    const float* __restrict__ x1, const unsigned short* __restrict__ yp,
    const float* __restrict__ b2, const int4* __restrict__ tokinfo,
    const float2* __restrict__ tokw, const int* __restrict__ offs,
    const float* __restrict__ g, const float* __restrict__ beta,
    float* __restrict__ out)
{
  int n = blockIdx.x, t = threadIdx.x;
  __shared__ float red[256];
  int4 ti = tokinfo[n]; float2 tw = tokw[n];
  const size_t s1 = (size_t)(offs[ti.x] + ti.y)*Dz;
  const size_t s2 = (size_t)(offs[ti.z] + ti.w)*Dz;
  const size_t CS = (size_t)SLOTSz*Dz;
  const float* b2a = b2 + (size_t)ti.x*Dz;
  const float* b2b = b2 + (size_t)ti.z*Dz;
  float vals[4]; float s = 0.f;
  #pragma unroll
  for (int i = 0; i < 4; ++i) {
    int d = t + i*256;
    float a0 = b2f(yp[s1 + d]);
    float a1 = b2f(yp[CS + s1 + d]);
    float a2 = b2f(yp[2*CS + s1 + d]);
    float a3 = b2f(yp[3*CS + s1 + d]);
    float c0 = b2f(yp[s2 + d]);
    float c1 = b2f(yp[CS + s2 + d]);
    float c2 = b2f(yp[2*CS + s2 + d]);
    float c3 = b2f(yp[3*CS + s2 + d]);
    float sumA = (a0 + a1) + (a2 + a3);
    float sumB = (c0 + c1) + (c2 + c3);
    float xv = x1[(size_t)n*Dz + d] + tw.x*(sumA + b2a[d]) + tw.y*(sumB + b2b[d]);
    vals[i] = xv; s += xv;
  }
  red[t] = s; __syncthreads();
  for (int st = 128; st; st >>= 1) { if (t < st) red[t] += red[t+st]; __syncthreads(); }
  float mean = red[0] * (1.0f/Dz);
  __syncthreads();
  float vsum = 0.f;
  #pragma unroll
  for (int i = 0; i < 4; ++i){ float dd = vals[i]-mean; vsum += dd*dd; }
  red[t] = vsum; __syncthreads();
  for (int st = 128; st; st >>= 1) { if (t < st) red[t] += red[t+st]; __syncthreads(); }
  float rs = rsqrtf(red[0]*(1.0f/Dz) + EPSz);
  #pragma unroll
  for (int i = 0; i < 4; ++i) {
    int d = t + i*256;
    out[(size_t)n*Dz + d] = (vals[i]-mean)*rs*g[d] + beta[d];
  }
}

extern "C" void kernel_launch(void* const* d_in, const int* in_sizes, int n_in,
                              void* d_out, int out_size, void* d_ws, size_t ws_size,
                              hipStream_t stream)
{
  const float* x  = (const float*)d_in[0];
  const float* Wq = (const float*)d_in[1];
  const float* bq = (const float*)d_in[2];
  const float* Wk = (const float*)d_in[3];
  const float* bk = (const float*)d_in[4];
  const float* Wv = (const float*)d_in[5];
  const float* bv = (const float*)d_in[6];
  const float* Wo = (const float*)d_in[7];
  const float* bo = (const float*)d_in[8];
  const float* Wg = (const float*)d_in[9];
  const float* bg = (const float*)d_in[10];
  const float* W1 = (const float*)d_in[11];
  const float* b1 = (const float*)d_in[12];
  const float* W2 = (const float*)d_in[13];
  const float* b2 = (const float*)d_in[14];
  const float* g1 = (const float*)d_in[15];
  const float* be1= (const float*)d_in[16];
  const float* g2 = (const float*)d_in[17];
  const float* be2= (const float*)d_in[18];
  float* out = (float*)d_out;

  const size_t PD = (size_t)Dz*Dz;
  const size_t ND = (size_t)Nz*Dz;
  unsigned short* Wqt = (unsigned short*)d_ws;
  unsigned short* Wkt = Wqt + PD;
  unsigned short* Wvt = Wkt + PD;
  unsigned short* Wot = Wvt + PD;
  unsigned short* W1t = Wot + PD;
  unsigned short* W2t = W1t + (size_t)Ez*FFz*Dz;
  unsigned short* hb  = W2t + (size_t)Ez*FFz*Dz;
  unsigned short* xb  = hb  + (size_t)SLOTSz*FFz;
  unsigned short* qkvb= xb  + ND;                 // [Nz][3072]
  unsigned short* aob = qkvb + (size_t)Nz*QKVSz;
  unsigned short* x1b = aob + ND;
  float* x1 = (float*)(x1b + ND);
  unsigned short* yp = (unsigned short*)(x1 + ND); // [4][SLOTS][Dz] bf16 (32MB)
  unsigned short* op = yp;                         // alias: [4][Nz][Dz] bf16
  float* bqkv = (float*)(yp + (size_t)4*SLOTSz*Dz);
  int4*  tokinfo = (int4*)(bqkv + QKVSz);
  float2* tokw   = (float2*)(tokinfo + Nz);
  int* counts  = (int*)(tokw + Nz);
  int* offs    = counts + Ez;
  int* toklist = offs + Ez + 1;
  int2* rbmap  = (int2*)(toklist + Ez*Nz);

  dim3 blk(256);
  // fused prologue: Wq/Wk/Wv/Wo transpose + bias concat + x->bf16 + counts=0
  prologue_k<<<3084, blk, 0, stream>>>(Wq, Wk, Wv, Wo, bq, bk, bv, x,
                                       Wqt, Wkt, Wvt, Wot, bqkv, xb, counts);

  // fused QKV with fused RoPE: [2048,1024] @ [1024,3072] -> qkvb
  gemm_proj<<<dim3(QKVSz/128, Nz/128), blk, 0, stream>>>(
      xb, Wqt, bqkv, qkvb, Nz, QKVSz, Dz, 1, 0, 1);

  // MEGA: attention (16.6KB LDS, XCD-swizzled) + W1/W2 transpose-convert
  mega_k<<<512 + 2*8192, blk, 0, stream>>>(qkvb, aob, W1, W1t, W2, W2t);

  // O projection: split-K x4 deterministic bf16 partials -> op[4][Nz][Dz]
  gemm_proj<<<dim3((Dz/128)*4, Nz/128), blk, 0, stream>>>(
      aob, Wot, nullptr, op, Nz, Dz, Dz, 4, 1, 0);

  // ln1 + fused gate/top-2/bucketing
  ln1_k<<<Nz, blk, 0, stream>>>(x, bo, op, g1, be1, Wg, bg, x1, x1b,
                                counts, toklist, tokinfo, tokw);
  prefix_k<<<1, dim3(64), 0, stream>>>(counts, offs, rbmap);
  moe_gemm1<<<dim3(FFz/128, NRB), blk, 0, stream>>>(x1b, W1t, b1, counts, offs, toklist, rbmap, hb);
  moe_gemm2<<<dim3((Dz/128)*4, NRB), blk, 0, stream>>>(hb, W2t, counts, offs, rbmap, yp);
  ln2_k<<<Nz, blk, 0, stream>>>(x1, yp, b2, tokinfo, tokw, offs, g2, be2, out);
}

// Round 16
// 333.774 us; speedup vs baseline: 1.0800x; 1.0608x over previous
//
#include <hip/hip_runtime.h>
#include <cmath>

#define Bz 2
#define Sz 1024
#define Dz 1024
#define Hz 16
#define HDz 64
#define Ez 8
#define FFz 4096
#define Nz (Bz*Sz)
#define SLOTSz (2*Nz)
#define QKVSz (3*Dz)
#define EPSz 1e-5f
#define NRB 40

typedef __attribute__((ext_vector_type(8))) short bf16x8;
typedef __attribute__((ext_vector_type(4))) short bf16x4;
typedef __attribute__((ext_vector_type(4))) float f32x4;
typedef __attribute__((ext_vector_type(8))) unsigned short ushortx8;

__device__ __forceinline__ float b2f(unsigned short u){
  union { unsigned int i; float f; } x; x.i = ((unsigned int)u) << 16; return x.f;
}
__device__ __forceinline__ unsigned short f2b(float f){
  union { float f; unsigned int i; } x; x.f = f;
  unsigned int r = x.i + 0x7FFFu + ((x.i >> 16) & 1u);
  return (unsigned short)(r >> 16);
}
__device__ __forceinline__ float erf_fast(float x){
  float ax = fabsf(x);
  float t = 1.0f/(1.0f + 0.3275911f*ax);
  float p = t*(0.254829592f + t*(-0.284496736f + t*(1.421413741f +
            t*(-1.453152027f + t*1.061405429f))));
  float r = 1.0f - p*__expf(-ax*ax);
  return copysignf(r, x);
}
__device__ __forceinline__ float gelu_f(float x){
  return 0.5f*x*(1.0f + erf_fast(x*0.70710678118654752f));
}
__device__ __forceinline__ void gload16(const void* g, void* l){
  __builtin_amdgcn_global_load_lds(
    (const __attribute__((address_space(1))) unsigned int*)g,
    (__attribute__((address_space(3))) unsigned int*)l, 16, 0, 0);
}

// ---------- shared transpose body: fp32 [R][C] tile -> bf16 [C][R] ----------
__device__ __forceinline__ void transpose_body(
    const float* __restrict__ in, unsigned short* __restrict__ out,
    int R, int C, int bx, int by, int tid, float (*tile)[65])
{
  int c0 = bx*64, r0 = by*64;
  int tx = tid & 15, ty = tid >> 4;
  #pragma unroll
  for (int i = 0; i < 4; ++i) {
    float4 v = *(const float4*)(in + (size_t)(r0+ty+16*i)*C + c0 + tx*4);
    tile[ty+16*i][tx*4+0] = v.x; tile[ty+16*i][tx*4+1] = v.y;
    tile[ty+16*i][tx*4+2] = v.z; tile[ty+16*i][tx*4+3] = v.w;
  }
  __syncthreads();
  int oc = tid >> 3, og = tid & 7;
  #pragma unroll
  for (int p = 0; p < 2; ++p) {
    int c = oc + p*32;
    ushortx8 u;
    #pragma unroll
    for (int j = 0; j < 8; ++j) u[j] = f2b(tile[og*8+j][c]);
    *(ushortx8*)(out + (size_t)(c0+c)*R + r0 + og*8) = u;
  }
}

// -- fused prologue: Wq/Wk/Wv/Wo transpose + bias concat + x->bf16 + counts=0 --
__global__ __launch_bounds__(256) void prologue_k(
    const float* __restrict__ Wq, const float* __restrict__ Wk,
    const float* __restrict__ Wv, const float* __restrict__ Wo,
    const float* __restrict__ bq, const float* __restrict__ bk,
    const float* __restrict__ bv, const float* __restrict__ x,
    unsigned short* __restrict__ Wqt, unsigned short* __restrict__ Wkt,
    unsigned short* __restrict__ Wvt, unsigned short* __restrict__ Wot,
    float* __restrict__ bqkv, unsigned short* __restrict__ xb,
    int* __restrict__ counts)
{
  __shared__ float tile[64][65];
  int id = blockIdx.x, t = threadIdx.x;
  if (id < 1024) {
    int which = id >> 8, rem = id & 255;
    const float* in = (which==0)?Wq:(which==1)?Wk:(which==2)?Wv:Wo;
    unsigned short* out = (which==0)?Wqt:(which==1)?Wkt:(which==2)?Wvt:Wot;
    transpose_body(in, out, Dz, Dz, rem & 15, rem >> 4, t, tile);
  } else if (id < 1024 + 2048) {
    int i = ((id-1024)*256 + t)*4;
    float4 v = *(const float4*)(x + i);
    ushort4 o; o.x=f2b(v.x); o.y=f2b(v.y); o.z=f2b(v.z); o.w=f2b(v.w);
    *(ushort4*)(xb + i) = o;
  } else {
    int i = (id - 3072)*256 + t;
    if (i < 3072) bqkv[i] = (i < 1024) ? bq[i] : (i < 2048 ? bk[i-1024] : bv[i-2048]);
    if (id == 3072 && t < Ez) counts[t] = 0;
  }
}

// ------- MFMA 128x128xK core: 3-buffer counted-vmcnt pipeline (round-7-proven
//         sync skeleton) + round-12 coalesced staging / swizzled reads -------
__device__ __forceinline__ void mfma_kloop(
    const unsigned short* __restrict__ pA0, const unsigned short* __restrict__ pA1,
    const unsigned short* __restrict__ pB0, const unsigned short* __restrict__ pB1,
    char* lds, int t, int K, f32x4 acc[4][4])
{
  const int lane = t & 63, w = t >> 6;
  const int wrOff = (w >> 1) * 4096;
  const int wcOff = (w & 1) * 4096;
  const int lr = lane & 15, q = lane >> 4;
  const int xq = (q ^ (lr & 3)) << 4;
  const int baseA = wrOff + lr*64 + xq;
  const int baseB = 8192 + wcOff + lr*64 + xq;
#define STAGEK(bi, k0) do { \
    char* _b = lds + (bi)*16384; \
    gload16(pA0 + (k0), _b + t*16); \
    gload16(pA1 + (k0), _b + 4096 + t*16); \
    gload16(pB0 + (k0), _b + 8192 + t*16); \
    gload16(pB1 + (k0), _b + 12288 + t*16); \
  } while(0)
#define WAITBAR4 do { __builtin_amdgcn_sched_barrier(0); \
    asm volatile("s_waitcnt vmcnt(4) lgkmcnt(0)\n\ts_barrier" ::: "memory"); \
    __builtin_amdgcn_sched_barrier(0); } while(0)
#define WAITBAR0 do { __builtin_amdgcn_sched_barrier(0); \
    asm volatile("s_waitcnt vmcnt(0) lgkmcnt(0)\n\ts_barrier" ::: "memory"); \
    __builtin_amdgcn_sched_barrier(0); } while(0)
  const int nt = K >> 5;
  STAGEK(0, 0);
  if (nt > 1) { STAGEK(1, 32); WAITBAR4; }
  else        {                WAITBAR0; }
  int cur = 0;
  for (int ti = 0; ti < nt; ++ti) {
    const bool more = (ti + 2 < nt);
    if (more) {
      int stg = cur + 2; if (stg >= 3) stg -= 3;
      STAGEK(stg, (ti + 2) << 5);
    }
    char* cb = lds + cur*16384;
    bf16x8 a[4], b[4];
    #pragma unroll
    for (int m = 0; m < 4; ++m) a[m] = *(const bf16x8*)(cb + baseA + m*1024);
    #pragma unroll
    for (int n = 0; n < 4; ++n) b[n] = *(const bf16x8*)(cb + baseB + n*1024);
    #pragma unroll
    for (int m = 0; m < 4; ++m)
      #pragma unroll
      for (int n = 0; n < 4; ++n)
        acc[m][n] = __builtin_amdgcn_mfma_f32_16x16x32_bf16(a[m], b[n], acc[m][n], 0, 0, 0);
    if (more) WAITBAR4; else WAITBAR0;
    cur += 1; if (cur >= 3) cur -= 3;
  }
#undef STAGEK
#undef WAITBAR4
#undef WAITBAR0
}

// ---------------- dense GEMM with optional split-K (deterministic) ----------------
__global__ __launch_bounds__(256) void gemm_proj(
    const unsigned short* __restrict__ A, const unsigned short* __restrict__ Bt,
    const float* __restrict__ bias, unsigned short* __restrict__ outb,
    int M, int Nn, int K, int KS, int mode, int doRope)
{
  __shared__ __align__(16) char lds[49152];
  const int t = threadIdx.x;
  const int nblk = Nn >> 7;
  const int chunk = blockIdx.x / nblk;
  const int n0 = (blockIdx.x - chunk*nblk) << 7;
  const int m0 = blockIdx.y << 7;
  const int Kc = K / KS;
  const int kbase = chunk * Kc;
  const int rr = t >> 2;
  const int ch = ((t & 3) ^ (rr & 3)) * 8;
  const unsigned short* pA0 = A + (size_t)(m0 + rr)*K + kbase + ch;
  const unsigned short* pA1 = pA0 + (size_t)64*K;
  const unsigned short* pB0 = Bt + (size_t)(n0 + rr)*K + kbase + ch;
  const unsigned short* pB1 = pB0 + (size_t)64*K;
  f32x4 acc[4][4] = {};
  mfma_kloop(pA0, pA1, pB0, pB1, lds, t, Kc, acc);
  const int lane = t & 63, w = t >> 6;
  const int wr = (w>>1)<<6, wc = (w&1)<<6, lq = lane>>4, lr = lane&15;
  if (mode == 0) {
    #pragma unroll
    for (int m = 0; m < 4; ++m)
      #pragma unroll
      for (int r = 0; r < 4; ++r) {
        int row = m0 + wr + m*16 + lq*4 + r;
        int s = row & (Sz-1);
        #pragma unroll
        for (int n = 0; n < 2; ++n) {
          int col = n0 + wc + n*16 + lr;
          float v0 = acc[m][n][r]   + bias[col];
          float v1 = acc[m][n+2][r] + bias[col+32];
          if (doRope && col < 2*Dz) {
            int i = n*16 + lr;
            float ang = (float)s * __powf(10000.0f, -(float)i*(1.0f/32.0f));
            float sn, cs; __sincosf(ang, &sn, &cs);
            float r0 = v0*cs - v1*sn;
            float r1 = v1*cs + v0*sn;
            v0 = r0; v1 = r1;
          }
          outb[(size_t)row*Nn + col]      = f2b(v0);
          outb[(size_t)row*Nn + col + 32] = f2b(v1);
        }
      }
  } else {
    #pragma unroll
    for (int m = 0; m < 4; ++m)
      #pragma unroll
      for (int r = 0; r < 4; ++r) {
        int row = m0 + wr + m*16 + lq*4 + r;
        #pragma unroll
        for (int n = 0; n < 4; ++n) {
          int col = n0 + wc + n*16 + lr;
          outb[((size_t)chunk*M + row)*Nn + col] = f2b(acc[m][n][r]);
        }
      }
  }
}

// ---------------- grouped MoE GEMM1 (row-block table) ----------------
__global__ __launch_bounds__(256) void moe_gemm1(
    const unsigned short* __restrict__ x1b, const unsigned short* __restrict__ W1t,
    const float* __restrict__ b1, const int* __restrict__ counts,
    const int* __restrict__ offs, const int* __restrict__ toklist,
    const int2* __restrict__ rbmap, unsigned short* __restrict__ hb)
{
  const int2 rbe = rbmap[blockIdx.y];
  if (rbe.x < 0) return;
  const int e = rbe.x, r0 = rbe.y, cnt = counts[e];
  __shared__ __align__(16) char lds[49152];
  const int t = threadIdx.x, n0 = blockIdx.x*128;
  const int rr = t >> 2;
  const int ch = ((t & 3) ^ (rr & 3)) * 8;
  const int rg0 = r0 + rr, rg1 = r0 + 64 + rr;
  const int tok0 = toklist[e*Nz + (rg0 < cnt ? rg0 : 0)];
  const int tok1 = toklist[e*Nz + (rg1 < cnt ? rg1 : 0)];
  const unsigned short* pA0 = x1b + (size_t)tok0*Dz + ch;
  const unsigned short* pA1 = x1b + (size_t)tok1*Dz + ch;
  const unsigned short* pB0 = W1t + ((size_t)e*FFz + n0 + rr)*Dz + ch;
  const unsigned short* pB1 = pB0 + (size_t)64*Dz;
  f32x4 acc[4][4] = {};
  mfma_kloop(pA0, pA1, pB0, pB1, lds, t, Dz, acc);
  const int lane = t & 63, w = t >> 6;
  const int wr = (w>>1)<<6, wc = (w&1)<<6, lq = lane>>4, lr = lane&15;
  const int base = offs[e] + r0;
  #pragma unroll
  for (int m = 0; m < 4; ++m)
    #pragma unroll
    for (int r = 0; r < 4; ++r) {
      int row = wr + m*16 + lq*4 + r;
      if (r0 + row >= cnt) continue;
      #pragma unroll
      for (int n = 0; n < 4; ++n) {
        int col = n0 + wc + n*16 + lr;
        hb[(size_t)(base+row)*FFz + col] = f2b(gelu_f(acc[m][n][r] + b1[e*FFz + col]));
      }
    }
}

// ------- grouped MoE GEMM2, split-K x4 -> per-chunk bf16 partial stores -------
__global__ __launch_bounds__(256) void moe_gemm2(
    const unsigned short* __restrict__ hb, const unsigned short* __restrict__ W2t,
    const int* __restrict__ counts, const int* __restrict__ offs,
    const int2* __restrict__ rbmap, unsigned short* __restrict__ yp)
{
  const int2 rbe = rbmap[blockIdx.y];
  if (rbe.x < 0) return;
  const int e = rbe.x, r0 = rbe.y, cnt = counts[e];
  __shared__ __align__(16) char lds[49152];
  const int t = threadIdx.x;
  const int chunk = blockIdx.x >> 3;
  const int n0 = (blockIdx.x & 7) << 7;
  const int kbase = chunk * (FFz/4);
  const int rr = t >> 2;
  const int ch = ((t & 3) ^ (rr & 3)) * 8;
  const int rg0 = r0 + rr, rg1 = r0 + 64 + rr;
  const int slot0 = offs[e] + (rg0 < cnt ? rg0 : 0);
  const int slot1 = offs[e] + (rg1 < cnt ? rg1 : 0);
  const unsigned short* pA0 = hb + (size_t)slot0*FFz + kbase + ch;
  const unsigned short* pA1 = hb + (size_t)slot1*FFz + kbase + ch;
  const unsigned short* pB0 = W2t + ((size_t)e*Dz + n0 + rr)*FFz + kbase + ch;
  const unsigned short* pB1 = pB0 + (size_t)64*FFz;
  f32x4 acc[4][4] = {};
  mfma_kloop(pA0, pA1, pB0, pB1, lds, t, FFz/4, acc);
  const int lane = t & 63, w = t >> 6;
  const int wr = (w>>1)<<6, wc = (w&1)<<6, lq = lane>>4, lr = lane&15;
  const int base = offs[e] + r0;
  #pragma unroll
  for (int m = 0; m < 4; ++m)
    #pragma unroll
    for (int r = 0; r < 4; ++r) {
      int row = wr + m*16 + lq*4 + r;
      if (r0 + row >= cnt) continue;
      #pragma unroll
      for (int n = 0; n < 4; ++n) {
        int col = n0 + wc + n*16 + lr;
        yp[((size_t)chunk*SLOTSz + base + row)*Dz + col] = f2b(acc[m][n][r]);
      }
    }
}

// ----- MEGA: attention (blocks 0..511, KVBLK=64, P aliased onto K, 16.6KB LDS)
//       + W1/W2 transpose-convert (rest) ----- (unchanged from round 15)
__global__ __launch_bounds__(256) void mega_k(
    const unsigned short* __restrict__ qkv, unsigned short* __restrict__ ao,
    const float* __restrict__ W1, unsigned short* __restrict__ W1t,
    const float* __restrict__ W2, unsigned short* __restrict__ W2t)
{
  __shared__ __align__(16) char smem[16640];
  const int bid = blockIdx.x;
  if (bid >= 512) {
    if (bid < 512 + 8192) {
      int rem = bid - 512; int e = rem >> 10; int r = rem & 1023;
      transpose_body(W1 + (size_t)e*Dz*FFz, W1t + (size_t)e*FFz*Dz, Dz, FFz,
                     r & 63, r >> 6, threadIdx.x, (float(*)[65])smem);
    } else {
      int rem = bid - 8704; int e = rem >> 10; int r = rem & 1023;
      transpose_body(W2 + (size_t)e*FFz*Dz, W2t + (size_t)e*Dz*FFz, FFz, Dz,
                     r & 15, r >> 4, threadIdx.x, (float(*)[65])smem);
    }
    return;
  }
  const int lb = ((bid & 7) << 6) | (bid >> 3);   // bijective on [0,512)
  char* Klds = smem;
  char* Vlds = smem + 8192;
  const unsigned short* q = qkv;
  const unsigned short* k = qkv + Dz;
  const unsigned short* v = qkv + 2*Dz;

  const int t = threadIdx.x;
  const int lane = t & 63, w = t >> 6;
  const int p15 = lane & 15, g = lane >> 4;
  const int bh = lb >> 4;
  const int qblk = lb & 15;
  const int b = bh >> 4, h = bh & 15;
  const size_t hoff = (size_t)h*HDz;
  const int q0 = qblk*64 + w*16;

  const size_t qrow = (size_t)(b*Sz + q0 + p15)*QKVSz + hoff;
  const bf16x8 qf0 = *(const bf16x8*)(q + qrow + 8*g);
  const bf16x8 qf1 = *(const bf16x8*)(q + qrow + 32 + 8*g);

  char* Pw = Klds + w*2048;

  float mrun = -INFINITY, lsum = 0.f;
  f32x4 acc_o[4] = {};

  const unsigned short* kbh = k + (size_t)(b*Sz)*QKVSz + hoff;
  const unsigned short* vbh = v + (size_t)(b*Sz)*QKVSz + hoff;

  for (int t0 = 0; t0 < Sz; t0 += 64) {
    __syncthreads();
    #pragma unroll
    for (int u = 0; u < 2; ++u) {
      int j = t + 256*u;
      int kkv = j >> 3, kdc = (j & 7) ^ (kkv & 7);
      gload16(kbh + (size_t)(t0 + kkv)*QKVSz + 8*kdc, Klds + j*16);
      int va = j >> 5, vbb = (j >> 3) & 3, vr = (j >> 1) & 3, vc = 8*(j & 1);
      gload16(vbh + (size_t)(t0 + 4*va + vr)*QKVSz + 16*vbb + vc, Vlds + j*16);
    }
    __syncthreads();

    f32x4 sc[4];
    #pragma unroll
    for (int mt = 0; mt < 4; ++mt) {
      int kv = mt*16 + p15;
      bf16x8 a0 = *(const bf16x8*)(Klds + kv*128 + ((g     ^ (kv & 7))*16));
      bf16x8 a1 = *(const bf16x8*)(Klds + kv*128 + (((g+4) ^ (kv & 7))*16));
      f32x4 z = {};
      z = __builtin_amdgcn_mfma_f32_16x16x32_bf16(a0, qf0, z, 0, 0, 0);
      z = __builtin_amdgcn_mfma_f32_16x16x32_bf16(a1, qf1, z, 0, 0, 0);
      sc[mt] = z;
    }

    float pmax = -INFINITY;
    #pragma unroll
    for (int mt = 0; mt < 4; ++mt)
      #pragma unroll
      for (int r = 0; r < 4; ++r) {
        sc[mt][r] *= 0.125f;
        pmax = fmaxf(pmax, sc[mt][r]);
      }
    pmax = fmaxf(pmax, __shfl_xor(pmax, 16));
    pmax = fmaxf(pmax, __shfl_xor(pmax, 32));
    float mnew = fmaxf(mrun, pmax);
    float resc = __expf(mrun - mnew);
    mrun = mnew;

    __syncthreads();   // all waves done reading K: safe to overwrite with P

    float ps = 0.f;
    #pragma unroll
    for (int mt = 0; mt < 4; ++mt) {
      float p0 = __expf(sc[mt][0] - mnew);
      float p1 = __expf(sc[mt][1] - mnew);
      float p2 = __expf(sc[mt][2] - mnew);
      float p3 = __expf(sc[mt][3] - mnew);
      ps += (p0 + p1) + (p2 + p3);
      ushort4 pk;
      pk.x = f2b(p0); pk.y = f2b(p1); pk.z = f2b(p2); pk.w = f2b(p3);
      *(ushort4*)(Pw + ((p15*128 + mt*32 + g*8) ^ ((p15 & 7) << 4))) = pk;
    }
    ps += __shfl_xor(ps, 16);
    ps += __shfl_xor(ps, 32);
    lsum = lsum*resc + ps;
    #pragma unroll
    for (int bb = 0; bb < 4; ++bb) {
      acc_o[bb][0] *= resc; acc_o[bb][1] *= resc;
      acc_o[bb][2] *= resc; acc_o[bb][3] *= resc;
    }

    #pragma unroll
    for (int bb = 0; bb < 4; ++bb) {
      #pragma unroll
      for (int kh = 0; kh < 2; ++kh) {
        const __attribute__((address_space(3))) char* vp =
          (const __attribute__((address_space(3))) char*)
            (Vlds + 4096*kh + 1024*g + 128*bb + 8*p15);
        bf16x4 v0, v1;
        asm volatile("ds_read_b64_tr_b16 %0, %2\n\t"
                     "ds_read_b64_tr_b16 %1, %2 offset:512\n\t"
                     "s_waitcnt lgkmcnt(0)"
                     : "=v"(v0), "=v"(v1) : "v"(vp) : "memory");
        __builtin_amdgcn_sched_barrier(0);
        union { bf16x4 hh[2]; bf16x8 full; } af;
        af.hh[0] = v0; af.hh[1] = v1;
        bf16x8 pf = *(const bf16x8*)(Pw + ((p15*128 + kh*64 + g*16) ^ ((p15 & 7) << 4)));
        acc_o[bb] = __builtin_amdgcn_mfma_f32_16x16x32_bf16(af.full, pf, acc_o[bb], 0, 0, 0);
      }
    }
  }

  const float inv = 1.0f / lsum;
  const size_t orow = (size_t)(b*Sz + q0 + p15)*Dz + hoff;
  #pragma unroll
  for (int bb = 0; bb < 4; ++bb) {
    ushort4 o;
    o.x = f2b(acc_o[bb][0]*inv);
    o.y = f2b(acc_o[bb][1]*inv);
    o.z = f2b(acc_o[bb][2]*inv);
    o.w = f2b(acc_o[bb][3]*inv);
    *(ushort4*)(ao + orow + 16*bb + 4*g) = o;
  }
}

// ------ LayerNorm 1 + fused gate: in = x + bo + sum4(bf16 partials) ------
__global__ __launch_bounds__(256) void ln1_k(
    const float* __restrict__ x, const float* __restrict__ bo,
    const unsigned short* __restrict__ op, const float* __restrict__ g,
    const float* __restrict__ beta, const float* __restrict__ Wg,
    const float* __restrict__ bg, float* __restrict__ outf,
    unsigned short* __restrict__ outb, int* __restrict__ counts,
    int* __restrict__ toklist, int4* __restrict__ tokinfo,
    float2* __restrict__ tokw)
{
  int n = blockIdx.x, t = threadIdx.x;
  __shared__ float red[256];
  float vals[4]; float s = 0.f;
  #pragma unroll
  for (int i = 0; i < 4; ++i) {
    int d = t + i*256;
    size_t idx = (size_t)n*Dz + d;
    float p0 = b2f(op[idx]);
    float p1 = b2f(op[(size_t)Nz*Dz + idx]);
    float p2 = b2f(op[(size_t)2*Nz*Dz + idx]);
    float p3 = b2f(op[(size_t)3*Nz*Dz + idx]);
    float xv = x[idx] + bo[d] + ((p0 + p1) + (p2 + p3));
    vals[i] = xv; s += xv;
  }
  red[t] = s; __syncthreads();
  for (int st = 128; st; st >>= 1) { if (t < st) red[t] += red[t+st]; __syncthreads(); }
  float mean = red[0] * (1.0f/Dz);
  __syncthreads();
  float vsum = 0.f;
  #pragma unroll
  for (int i = 0; i < 4; ++i){ float dd = vals[i]-mean; vsum += dd*dd; }
  red[t] = vsum; __syncthreads();
  for (int st = 128; st; st >>= 1) { if (t < st) red[t] += red[t+st]; __syncthreads(); }
  float rs = rsqrtf(red[0]*(1.0f/Dz) + EPSz);
  float ga[8] = {0,0,0,0,0,0,0,0};
  #pragma unroll
  for (int i = 0; i < 4; ++i) {
    int d = t + i*256;
    float o = (vals[i]-mean)*rs*g[d] + beta[d];
    outf[(size_t)n*Dz + d] = o;
    outb[(size_t)n*Dz + d] = f2b(o);
    const float4* wp = (const float4*)(Wg + (size_t)d*Ez);
    float4 w0 = wp[0], w1 = wp[1];
    ga[0] += o*w0.x; ga[1] += o*w0.y; ga[2] += o*w0.z; ga[3] += o*w0.w;
    ga[4] += o*w1.x; ga[5] += o*w1.y; ga[6] += o*w1.z; ga[7] += o*w1.w;
  }
  #pragma unroll
  for (int e = 0; e < 8; ++e)
    #pragma unroll
    for (int off = 32; off; off >>= 1) ga[e] += __shfl_xor(ga[e], off);
  __syncthreads();
  if ((t & 63) == 0) {
    #pragma unroll
    for (int e = 0; e < 8; ++e) red[(t >> 6)*8 + e] = ga[e];
  }
  __syncthreads();
  if (t == 0) {
    float lg[8]; float mx = -INFINITY;
    #pragma unroll
    for (int e = 0; e < 8; ++e){
      lg[e] = (red[e] + red[8+e]) + (red[16+e] + red[24+e]) + bg[e];
      mx = fmaxf(mx, lg[e]);
    }
    float p[8];
    #pragma unroll
    for (int e = 0; e < 8; ++e) p[e] = __expf(lg[e]-mx);
    int e1 = 0; float m1 = p[0];
    for (int e = 1; e < 8; ++e) if (p[e] > m1){ m1 = p[e]; e1 = e; }
    int e2 = -1; float m2 = -INFINITY;
    for (int e = 0; e < 8; ++e) if (e != e1 && p[e] > m2){ m2 = p[e]; e2 = e; }
    float inv = 1.0f/(m1+m2);
    int p1 = atomicAdd(&counts[e1], 1); toklist[e1*Nz + p1] = n;
    int p2 = atomicAdd(&counts[e2], 1); toklist[e2*Nz + p2] = n;
    tokinfo[n] = make_int4(e1, p1, e2, p2);
    tokw[n] = make_float2(m1*inv, m2*inv);
  }
}

// ---------------- prefix + row-block table ----------------
__global__ void prefix_k(const int* __restrict__ counts, int* __restrict__ offs,
                         int2* __restrict__ rbmap){
  if (threadIdx.x == 0 && blockIdx.x == 0) {
    int s = 0;
    for (int e = 0; e < Ez; ++e){ offs[e] = s; s += counts[e]; }
    offs[Ez] = s;
    int rb = 0;
    for (int e = 0; e < Ez; ++e) {
      int nrb = (counts[e] + 127) >> 7;
      for (int i = 0; i < nrb; ++i) rbmap[rb++] = make_int2(e, i*128);
    }
    for (; rb < NRB; ++rb) rbmap[rb] = make_int2(-1, 0);
  }
}

// ------- final combine + LayerNorm (b2 + fixed-order bf16 partial sum) -------
__global__ __launch_bounds__(256) void ln2_k(
    const float* __restrict__ x1, const unsigned short* __restrict__ yp,
    const float* __restrict__ b2, const int4* __restrict__ tokinfo,
    const float2* __restrict__ tokw, const int* __restrict__ offs,
    const float* __restrict__ g, const float* __restrict__ beta,
    float* __restrict__ out)
{
  int n = blockIdx.x, t = threadIdx.x;
  __shared__ float red[256];
  int4 ti = tokinfo[n]; float2 tw = tokw[n];
  const size_t s1 = (size_t)(offs[ti.x] + ti.y)*Dz;
  const size_t s2 = (size_t)(offs[ti.z] + ti.w)*Dz;
  const size_t CS = (size_t)SLOTSz*Dz;
  const float* b2a = b2 + (size_t)ti.x*Dz;
  const float* b2b = b2 + (size_t)ti.z*Dz;
  float vals[4]; float s = 0.f;
  #pragma unroll
  for (int i = 0; i < 4; ++i) {
    int d = t + i*256;
    float a0 = b2f(yp[s1 + d]);
    float a1 = b2f(yp[CS + s1 + d]);
    float a2 = b2f(yp[2*CS + s1 + d]);
    float a3 = b2f(yp[3*CS + s1 + d]);
    float c0 = b2f(yp[s2 + d]);
    float c1 = b2f(yp[CS + s2 + d]);
    float c2 = b2f(yp[2*CS + s2 + d]);
    float c3 = b2f(yp[3*CS + s2 + d]);
    float sumA = (a0 + a1) + (a2 + a3);
    float sumB = (c0 + c1) + (c2 + c3);
    float xv = x1[(size_t)n*Dz + d] + tw.x*(sumA + b2a[d]) + tw.y*(sumB + b2b[d]);
    vals[i] = xv; s += xv;
  }
  red[t] = s; __syncthreads();
  for (int st = 128; st; st >>= 1) { if (t < st) red[t] += red[t+st]; __syncthreads(); }
  float mean = red[0] * (1.0f/Dz);
  __syncthreads();
  float vsum = 0.f;
  #pragma unroll
  for (int i = 0; i < 4; ++i){ float dd = vals[i]-mean; vsum += dd*dd; }
  red[t] = vsum; __syncthreads();
  for (int st = 128; st; st >>= 1) { if (t < st) red[t] += red[t+st]; __syncthreads(); }
  float rs = rsqrtf(red[0]*(1.0f/Dz) + EPSz);
  #pragma unroll
  for (int i = 0; i < 4; ++i) {
    int d = t + i*256;
    out[(size_t)n*Dz + d] = (vals[i]-mean)*rs*g[d] + beta[d];
  }
}

extern "C" void kernel_launch(void* const* d_in, const int* in_sizes, int n_in,
                              void* d_out, int out_size, void* d_ws, size_t ws_size,
                              hipStream_t stream)
{
  const float* x  = (const float*)d_in[0];
  const float* Wq = (const float*)d_in[1];
  const float* bq = (const float*)d_in[2];
  const float* Wk = (const float*)d_in[3];
  const float* bk = (const float*)d_in[4];
  const float* Wv = (const float*)d_in[5];
  const float* bv = (const float*)d_in[6];
  const float* Wo = (const float*)d_in[7];
  const float* bo = (const float*)d_in[8];
  const float* Wg = (const float*)d_in[9];
  const float* bg = (const float*)d_in[10];
  const float* W1 = (const float*)d_in[11];
  const float* b1 = (const float*)d_in[12];
  const float* W2 = (const float*)d_in[13];
  const float* b2 = (const float*)d_in[14];
  const float* g1 = (const float*)d_in[15];
  const float* be1= (const float*)d_in[16];
  const float* g2 = (const float*)d_in[17];
  const float* be2= (const float*)d_in[18];
  float* out = (float*)d_out;

  const size_t PD = (size_t)Dz*Dz;
  const size_t ND = (size_t)Nz*Dz;
  unsigned short* Wqt = (unsigned short*)d_ws;
  unsigned short* Wkt = Wqt + PD;
  unsigned short* Wvt = Wkt + PD;
  unsigned short* Wot = Wvt + PD;
  unsigned short* W1t = Wot + PD;
  unsigned short* W2t = W1t + (size_t)Ez*FFz*Dz;
  unsigned short* hb  = W2t + (size_t)Ez*FFz*Dz;
  unsigned short* xb  = hb  + (size_t)SLOTSz*FFz;
  unsigned short* qkvb= xb  + ND;                 // [Nz][3072]
  unsigned short* aob = qkvb + (size_t)Nz*QKVSz;
  unsigned short* x1b = aob + ND;
  float* x1 = (float*)(x1b + ND);
  unsigned short* yp = (unsigned short*)(x1 + ND); // [4][SLOTS][Dz] bf16 (32MB)
  unsigned short* op = yp;                         // alias: [4][Nz][Dz] bf16
  float* bqkv = (float*)(yp + (size_t)4*SLOTSz*Dz);
  int4*  tokinfo = (int4*)(bqkv + QKVSz);
  float2* tokw   = (float2*)(tokinfo + Nz);
  int* counts  = (int*)(tokw + Nz);
  int* offs    = counts + Ez;
  int* toklist = offs + Ez + 1;
  int2* rbmap  = (int2*)(toklist + Ez*Nz);

  dim3 blk(256);
  // fused prologue: Wq/Wk/Wv/Wo transpose + bias concat + x->bf16 + counts=0
  prologue_k<<<3084, blk, 0, stream>>>(Wq, Wk, Wv, Wo, bq, bk, bv, x,
                                       Wqt, Wkt, Wvt, Wot, bqkv, xb, counts);

  // fused QKV with fused RoPE: [2048,1024] @ [1024,3072] -> qkvb
  gemm_proj<<<dim3(QKVSz/128, Nz/128), blk, 0, stream>>>(
      xb, Wqt, bqkv, qkvb, Nz, QKVSz, Dz, 1, 0, 1);

  // MEGA: attention (16.6KB LDS, XCD-swizzled) + W1/W2 transpose-convert
  mega_k<<<512 + 2*8192, blk, 0, stream>>>(qkvb, aob, W1, W1t, W2, W2t);

  // O projection: split-K x4 deterministic bf16 partials -> op[4][Nz][Dz]
  gemm_proj<<<dim3((Dz/128)*4, Nz/128), blk, 0, stream>>>(
      aob, Wot, nullptr, op, Nz, Dz, Dz, 4, 1, 0);

  // ln1 + fused gate/top-2/bucketing
  ln1_k<<<Nz, blk, 0, stream>>>(x, bo, op, g1, be1, Wg, bg, x1, x1b,
                                counts, toklist, tokinfo, tokw);
  prefix_k<<<1, dim3(64), 0, stream>>>(counts, offs, rbmap);
  moe_gemm1<<<dim3(FFz/128, NRB), blk, 0, stream>>>(x1b, W1t, b1, counts, offs, toklist, rbmap, hb);
  moe_gemm2<<<dim3((Dz/128)*4, NRB), blk, 0, stream>>>(hb, W2t, counts, offs, rbmap, yp);
  ln2_k<<<Nz, blk, 0, stream>>>(x1, yp, b2, tokinfo, tokw, offs, g2, be2, out);
}